// Round 2
// baseline (123.467 us; speedup 1.0000x reference)
//
#include <hip/hip_runtime.h>

#define BB 4
#define SS 256
#define DD 512
#define CC 128
#define NC 64

// ---------------------------------------------------------------------------
// Kernel 1 (text): 64 blocks x 512 thr. Block = (batch b, chunk q of 16 rows).
// Computes ks/vs for its 16 rows entirely in LDS (never materialized to HBM),
// then writes PARTIAL M (64x64), Ks (64), Vs (64) for that chunk.
// ---------------------------------------------------------------------------
__global__ __launch_bounds__(512) void text_kernel(
    const float* __restrict__ s, const float* __restrict__ a,
    const float* __restrict__ Wks, const float* __restrict__ bks,
    const float* __restrict__ Wvs, const float* __restrict__ bvs,
    float* __restrict__ Mpart, float* __restrict__ Kspart,
    float* __restrict__ Vspart)
{
    __shared__ float tel[16][DD];    // 32 KB: 16 masked text rows
    __shared__ float ksl[16][NC];    // 4 KB
    __shared__ float vsl[16][NC];    // 4 KB

    const int t = threadIdx.x;           // 0..511
    const int w = t >> 6, lane = t & 63;
    const int b = blockIdx.x >> 4, q = blockIdx.x & 15;
    const int srow0 = b * SS + q * 16;   // global text-row base

    // ---- stage te = s * a (16 rows x 512), coalesced float4 ----
    {
        const float4* s4 = (const float4*)(s + (size_t)srow0 * DD);
        for (int i = t; i < 2048; i += 512) {      // 2048 float4 = 16*512 f
            const int r = i >> 7;                  // 128 float4 per row
            const float am = a[srow0 + r];
            float4 v = s4[i];
            v.x *= am; v.y *= am; v.z *= am; v.w *= am;
            ((float4*)&tel[0][0])[i] = v;
        }
    }
    __syncthreads();

    // ---- projection: wave w -> mat m = w&1 (ks/vs), rows 4*(w>>1)..+3 ----
    {
        const int m = w & 1, rg = w >> 1;          // rg in [0,4)
        const float* __restrict__ Wm = m ? Wvs : Wks;
        const float* __restrict__ bm = m ? bvs : bks;
        const int ksub = lane >> 4;                // 0..3
        const int cg = (lane & 15) * 4;            // col group base
        float4 acc[4] = {};
        #pragma unroll 4
        for (int j = 0; j < 128; ++j) {            // k = 4j+ksub covers [0,512)
            const int k = 4 * j + ksub;
            const float4 wv = *(const float4*)(Wm + (size_t)k * NC + cg);
            #pragma unroll
            for (int r = 0; r < 4; ++r) {
                const float tv = tel[rg * 4 + r][k];
                acc[r].x = fmaf(tv, wv.x, acc[r].x);
                acc[r].y = fmaf(tv, wv.y, acc[r].y);
                acc[r].z = fmaf(tv, wv.z, acc[r].z);
                acc[r].w = fmaf(tv, wv.w, acc[r].w);
            }
        }
        #pragma unroll
        for (int off = 16; off <= 32; off <<= 1) {
            #pragma unroll
            for (int r = 0; r < 4; ++r) {
                acc[r].x += __shfl_down(acc[r].x, off);
                acc[r].y += __shfl_down(acc[r].y, off);
                acc[r].z += __shfl_down(acc[r].z, off);
                acc[r].w += __shfl_down(acc[r].w, off);
            }
        }
        if (ksub == 0) {
            const float4 bb = *(const float4*)(bm + cg);
            float (*dst)[NC] = m ? vsl : ksl;
            #pragma unroll
            for (int r = 0; r < 4; ++r) {
                float4 v;
                v.x = acc[r].x + bb.x; v.y = acc[r].y + bb.y;
                v.z = acc[r].z + bb.z; v.w = acc[r].w + bb.w;
                *(float4*)&dst[rg * 4 + r][cg] = v;
            }
        }
    }
    __syncthreads();

    // ---- partial M[c][d] = sum_{s in chunk} vs[s][c]*ks[s][d] ----
    {
        const int c = t >> 3;                 // 0..63
        const int d0 = (t & 7) * 8;           // 0,8,..,56
        float4 A0 = {0,0,0,0}, A1 = {0,0,0,0};
        #pragma unroll
        for (int ss = 0; ss < 16; ++ss) {
            const float vv = vsl[ss][c];
            const float4 k0 = *(const float4*)&ksl[ss][d0];
            const float4 k1 = *(const float4*)&ksl[ss][d0 + 4];
            A0.x = fmaf(vv, k0.x, A0.x); A0.y = fmaf(vv, k0.y, A0.y);
            A0.z = fmaf(vv, k0.z, A0.z); A0.w = fmaf(vv, k0.w, A0.w);
            A1.x = fmaf(vv, k1.x, A1.x); A1.y = fmaf(vv, k1.y, A1.y);
            A1.z = fmaf(vv, k1.z, A1.z); A1.w = fmaf(vv, k1.w, A1.w);
        }
        float* Mp = Mpart + ((size_t)(b * 16 + q)) * (NC * NC) + c * NC + d0;
        *(float4*)Mp = A0;
        *(float4*)(Mp + 4) = A1;
    }
    // ---- partial Ks/Vs (column sums over the 16 rows) ----
    if (t < 128) {
        const int m = t >> 6, d = t & 63;
        const float (*src)[NC] = m ? vsl : ksl;
        float sum = 0.f;
        #pragma unroll
        for (int ss = 0; ss < 16; ++ss) sum += src[ss][d];
        float* dst = m ? Vspart : Kspart;
        dst[(b * 16 + q) * NC + d] = sum;
    }
}

// ---------------------------------------------------------------------------
// Kernel 2 (pixel): 256 blocks x 1024 thr, 16 px/block. Per block:
//  - sum the 16 M/Ks/Vs partials of its batch into LDS,
//  - compute its own q/kx/vx projections from x (x tile already needed
//    for the residual; kills the P round-trip),
//  - attention + out proj + residual + LN (proven code, px scaled 4->16).
// ---------------------------------------------------------------------------
__global__ __launch_bounds__(1024) void pixel_kernel(
    const float* __restrict__ x,
    const float* __restrict__ Wq,  const float* __restrict__ bq,
    const float* __restrict__ Wkx, const float* __restrict__ bkx,
    const float* __restrict__ Wvx, const float* __restrict__ bvx,
    const float* __restrict__ Wout, const float* __restrict__ bout,
    const float* __restrict__ ln_scale, const float* __restrict__ ln_bias,
    const float* __restrict__ Mpart, const float* __restrict__ Kspart,
    const float* __restrict__ Vspart,
    float* __restrict__ out)
{
    __shared__ float Ml[NC * 65];          // stride 65 -> conflict-free rows
    __shared__ float projl[16][192];       // q | kx | vx per pixel
    __shared__ float xl[16][CC];
    __shared__ float rsl[16][NC];
    __shared__ float mxl[16][NC];
    __shared__ float outl[16][NC];
    __shared__ float Ksl[NC], Vsl[NC];
    __shared__ float redl[8][2][4];

    const int t = threadIdx.x;             // 0..1023
    const int w = t >> 6, lane = t & 63;   // 16 waves
    const int px0g = blockIdx.x * 16;
    const int b = blockIdx.x >> 6;         // 64 blocks per batch

    // ---- load x tile (residual + xproj input) ----
    if (t < 512)
        ((float4*)&xl[0][0])[t] = ((const float4*)(x + (size_t)px0g * CC))[t];

    // ---- sum 16 M partials: 1 float4 per thread, 16 coalesced loads ----
    {
        const float4* Mp4 = (const float4*)(Mpart + (size_t)b * 16 * (NC * NC));
        float4 acc = {0,0,0,0};
        #pragma unroll
        for (int q = 0; q < 16; ++q) {
            const float4 v = Mp4[q * 1024 + t];
            acc.x += v.x; acc.y += v.y; acc.z += v.z; acc.w += v.w;
        }
        const int c = t >> 4, dq = t & 15;   // row c, float4-slot dq
        float* dst = &Ml[c * 65 + dq * 4];   // stride 65: scalar stores
        dst[0] = acc.x; dst[1] = acc.y; dst[2] = acc.z; dst[3] = acc.w;
    }
    // ---- sum Ks/Vs partials ----
    if (t < 128) {
        const int m = t >> 6, d = t & 63;
        const float* Pp = (m ? Vspart : Kspart) + b * 16 * NC + d;
        float sum = 0.f;
        #pragma unroll
        for (int q = 0; q < 16; ++q) sum += Pp[q * NC];
        (m ? Vsl : Ksl)[d] = sum;
    }
    __syncthreads();

    // ---- x projections: wave group g=w>>2 -> px quad [4g,4g+4), mg=w&3 ----
    {
        const int g = w >> 2, mg = w & 3;
        if (mg < 3) {
            const float* __restrict__ Wm = (mg == 0) ? Wq : (mg == 1 ? Wkx : Wvx);
            const float* __restrict__ bm = (mg == 0) ? bq : (mg == 1 ? bkx : bvx);
            const int ksub = lane >> 4;
            const int cg = (lane & 15) * 4;
            float4 acc[4] = {};
            #pragma unroll 4
            for (int j = 0; j < 32; ++j) {
                const int k = 4 * j + ksub;
                const float4 wv = *(const float4*)(Wm + (size_t)k * NC + cg);
                #pragma unroll
                for (int p = 0; p < 4; ++p) {
                    const float xv = xl[g * 4 + p][k];
                    acc[p].x = fmaf(xv, wv.x, acc[p].x);
                    acc[p].y = fmaf(xv, wv.y, acc[p].y);
                    acc[p].z = fmaf(xv, wv.z, acc[p].z);
                    acc[p].w = fmaf(xv, wv.w, acc[p].w);
                }
            }
            #pragma unroll
            for (int p = 0; p < 4; ++p) {
                #pragma unroll
                for (int off = 16; off <= 32; off <<= 1) {
                    acc[p].x += __shfl_down(acc[p].x, off);
                    acc[p].y += __shfl_down(acc[p].y, off);
                    acc[p].z += __shfl_down(acc[p].z, off);
                    acc[p].w += __shfl_down(acc[p].w, off);
                }
            }
            if (ksub == 0) {
                const float4 bb = *(const float4*)(bm + cg);
                #pragma unroll
                for (int p = 0; p < 4; ++p) {
                    float4 v;
                    v.x = acc[p].x + bb.x; v.y = acc[p].y + bb.y;
                    v.z = acc[p].z + bb.z; v.w = acc[p].w + bb.w;
                    *(float4*)&projl[g * 4 + p][mg * 64 + cg] = v;
                }
            }
        }
    }
    __syncthreads();

    // ---- pass 1: wave = pixel, lane = row c: softmax stats ----
    {
        const int px = w, c = lane;
        const float vxc = projl[px][128 + c];
        const float qc  = projl[px][c];
        const float uc  = fmaf(256.0f, vxc, Vsl[c]);
        float mx = -3.4e38f;
        #pragma unroll
        for (int d = 0; d < NC; ++d) {
            const float A = fmaf(uc, projl[px][64 + d],
                                 fmaf(vxc, Ksl[d], Ml[c * 65 + d])) * 0.125f;
            mx = fmaxf(mx, A);
        }
        float sum = 0.f;
        #pragma unroll
        for (int d = 0; d < NC; ++d) {
            const float A = fmaf(uc, projl[px][64 + d],
                                 fmaf(vxc, Ksl[d], Ml[c * 65 + d])) * 0.125f;
            sum += __expf(A - mx);
        }
        rsl[px][c] = qc / sum;
        mxl[px][c] = mx;
    }
    __syncthreads();

    // ---- pass 2: wave = pixel, lane = col d ----
    {
        const int px = w, d = lane;
        const float kxd = projl[px][64 + d];
        const float Ksd = Ksl[d];
        float acc = 0.f;
        #pragma unroll 4
        for (int c = 0; c < NC; ++c) {
            const float vxc = projl[px][128 + c];
            const float uc = fmaf(256.0f, vxc, Vsl[c]);
            const float A = fmaf(uc, kxd, fmaf(vxc, Ksd, Ml[c * 65 + d])) * 0.125f;
            acc = fmaf(rsl[px][c], __expf(A - mxl[px][c]), acc);
        }
        outl[px][d] = acc;
    }
    __syncthreads();

    // ---- out proj + residual + layernorm (8 px-pairs x 128 thr) ----
    {
        const int col = t & 127;
        const int pxg = t >> 7;                 // 0..7
        const int px0 = 2 * pxg, px1 = px0 + 1;
        float acc0 = 0.f, acc1 = 0.f;
        #pragma unroll 4
        for (int k = 0; k < NC; ++k) {
            const float wv = Wout[k * CC + col];
            acc0 = fmaf(outl[px0][k], wv, acc0);
            acc1 = fmaf(outl[px1][k], wv, acc1);
        }
        const float bb = bout[col];
        const float y0 = acc0 + bb + xl[px0][col];
        const float y1 = acc1 + bb + xl[px1][col];

        float s10 = y0, s20 = y0 * y0, s11 = y1, s21 = y1 * y1;
        #pragma unroll
        for (int off = 32; off >= 1; off >>= 1) {
            s10 += __shfl_down(s10, off);
            s20 += __shfl_down(s20, off);
            s11 += __shfl_down(s11, off);
            s21 += __shfl_down(s21, off);
        }
        const int half = (t >> 6) & 1;
        if (lane == 0) {
            redl[pxg][half][0] = s10; redl[pxg][half][1] = s20;
            redl[pxg][half][2] = s11; redl[pxg][half][3] = s21;
        }
        __syncthreads();
        const float S10 = redl[pxg][0][0] + redl[pxg][1][0];
        const float S20 = redl[pxg][0][1] + redl[pxg][1][1];
        const float S11 = redl[pxg][0][2] + redl[pxg][1][2];
        const float S21 = redl[pxg][0][3] + redl[pxg][1][3];
        const float mu0 = S10 * (1.f / 128.f);
        const float var0 = S20 * (1.f / 128.f) - mu0 * mu0;
        const float mu1 = S11 * (1.f / 128.f);
        const float var1 = S21 * (1.f / 128.f) - mu1 * mu1;
        const float r0 = rsqrtf(var0 + 1e-6f), r1 = rsqrtf(var1 + 1e-6f);
        const float gg = ln_scale[col], be = ln_bias[col];
        out[(size_t)(px0g + px0) * CC + col] = (y0 - mu0) * r0 * gg + be;
        out[(size_t)(px0g + px1) * CC + col] = (y1 - mu1) * r1 * gg + be;
    }
}

// ---------------------------------------------------------------------------
extern "C" void kernel_launch(void* const* d_in, const int* in_sizes, int n_in,
                              void* d_out, int out_size, void* d_ws, size_t ws_size,
                              hipStream_t stream) {
    const float* x        = (const float*)d_in[0];
    const float* s        = (const float*)d_in[1];
    const float* a        = (const float*)d_in[2];
    const float* Wq       = (const float*)d_in[3];
    const float* bq       = (const float*)d_in[4];
    const float* Wkx      = (const float*)d_in[5];
    const float* bkx      = (const float*)d_in[6];
    const float* Wvx      = (const float*)d_in[7];
    const float* bvx      = (const float*)d_in[8];
    const float* Wks      = (const float*)d_in[9];
    const float* bks      = (const float*)d_in[10];
    const float* Wvs      = (const float*)d_in[11];
    const float* bvs      = (const float*)d_in[12];
    const float* Wout     = (const float*)d_in[13];
    const float* bout     = (const float*)d_in[14];
    const float* ln_scale = (const float*)d_in[15];
    const float* ln_bias  = (const float*)d_in[16];

    float* ws     = (float*)d_ws;
    float* Mpart  = ws;               // 64 * 4096 = 262144 floats
    float* Kspart = ws + 262144;      // 64 * 64   = 4096
    float* Vspart = ws + 266240;      // 64 * 64   = 4096

    text_kernel<<<64, 512, 0, stream>>>(
        s, a, Wks, bks, Wvs, bvs, Mpart, Kspart, Vspart);
    pixel_kernel<<<256, 1024, 0, stream>>>(
        x, Wq, bq, Wkx, bkx, Wvx, bvx, Wout, bout, ln_scale, ln_bias,
        Mpart, Kspart, Vspart, (float*)d_out);
}

// Round 3
// 119.009 us; speedup vs baseline: 1.0375x; 1.0375x over previous
//
#include <hip/hip_runtime.h>
#include <hip/hip_bf16.h>

#define BB 4
#define SS 256
#define DD 512
#define CC 128
#define NC 64
#define PXB 4    // pixels per block in pixel kernel

// ---------------------------------------------------------------------------
// Kernel 1 (fused): blocks 0..511 = x projections (8 px/block),
//                   blocks 512..767 = text projections (4 rows/block).
// Both roles: 256 threads, float4 weight loads, shuffle-reduce over k-sublanes.
// xproj output P[px][0:64]=q, [64:128]=kx, [128:192]=vx.
// Text role widened 2->4 rows/block: halves Wks/Wvs L2 re-reads (128->64 MB).
// ---------------------------------------------------------------------------
__global__ __launch_bounds__(256) void fused_proj_kernel(
    const float* __restrict__ x,
    const float* __restrict__ Wq,  const float* __restrict__ bq,
    const float* __restrict__ Wkx, const float* __restrict__ bkx,
    const float* __restrict__ Wvx, const float* __restrict__ bvx,
    const float* __restrict__ s, const float* __restrict__ a,
    const float* __restrict__ Wks, const float* __restrict__ bks,
    const float* __restrict__ Wvs, const float* __restrict__ bvs,
    float* __restrict__ P, float* __restrict__ ksw, float* __restrict__ vsw)
{
    __shared__ float tel[4][DD];          // text role: 4 masked rows
    __shared__ float part[2][2][4][NC];   // text role: [mat][half][row][col]
    __shared__ float xl[8][CC];           // xproj role

    const int t = threadIdx.x;
    const int w = t >> 6, lane = t & 63;

    if (blockIdx.x < 512) {
        // ---------------- xproj role ----------------
        const int px0 = blockIdx.x * 8;
        {
            const float4* x4 = (const float4*)(x + (size_t)px0 * CC);
            ((float4*)&xl[0][0])[t] = x4[t];    // 256 float4 = 8*128 floats
        }
        __syncthreads();
        if (w < 3) {
            const float* __restrict__ Wm = (w == 0) ? Wq : (w == 1 ? Wkx : Wvx);
            const float* __restrict__ bm = (w == 0) ? bq : (w == 1 ? bkx : bvx);
            const int ksub = lane >> 4;        // 0..3
            const int cg = (lane & 15) * 4;    // col group base
            float4 acc[8] = {};
            #pragma unroll 4
            for (int j = 0; j < 32; ++j) {
                const int k = 4 * j + ksub;
                const float4 wv = *(const float4*)(Wm + (size_t)k * NC + cg);
                #pragma unroll
                for (int px = 0; px < 8; ++px) {
                    const float xv = xl[px][k];
                    acc[px].x = fmaf(xv, wv.x, acc[px].x);
                    acc[px].y = fmaf(xv, wv.y, acc[px].y);
                    acc[px].z = fmaf(xv, wv.z, acc[px].z);
                    acc[px].w = fmaf(xv, wv.w, acc[px].w);
                }
            }
            #pragma unroll
            for (int px = 0; px < 8; ++px) {
                #pragma unroll
                for (int off = 16; off <= 32; off <<= 1) {
                    acc[px].x += __shfl_down(acc[px].x, off);
                    acc[px].y += __shfl_down(acc[px].y, off);
                    acc[px].z += __shfl_down(acc[px].z, off);
                    acc[px].w += __shfl_down(acc[px].w, off);
                }
            }
            if (ksub == 0) {
                const float4 bb = *(const float4*)(bm + cg);
                #pragma unroll
                for (int px = 0; px < 8; ++px) {
                    float4 v;
                    v.x = acc[px].x + bb.x; v.y = acc[px].y + bb.y;
                    v.z = acc[px].z + bb.z; v.w = acc[px].w + bb.w;
                    *(float4*)(P + (size_t)(px0 + px) * 192 + w * 64 + cg) = v;
                }
            }
        }
    } else {
        // ---------------- text role: 4 rows per block ----------------
        const int row0 = (blockIdx.x - 512) * 4;
        {
            // stage te = s * a : 4 rows x 512 = 512 float4, 2 per thread
            const float4* s4 = (const float4*)(s + (size_t)row0 * DD);
            #pragma unroll
            for (int i = t; i < 512; i += 256) {
                const int r = i >> 7;              // 128 float4 per row
                const float am = a[row0 + r];
                float4 v = s4[i];
                v.x *= am; v.y *= am; v.z *= am; v.w *= am;
                ((float4*)&tel[0][0])[i] = v;
            }
        }
        __syncthreads();

        const int m = w & 1, h = w >> 1;       // mat, k-half
        const int kb = h * 256;
        const int cg = (lane & 15) * 4;
        const int ksub = lane >> 4;
        const float* __restrict__ Wm = m ? Wvs : Wks;

        float4 acc[4] = {};
        #pragma unroll 4
        for (int j = 0; j < 64; ++j) {
            const int k = kb + 4 * j + ksub;
            const float4 wv = *(const float4*)(Wm + (size_t)k * NC + cg);
            #pragma unroll
            for (int r = 0; r < 4; ++r) {
                const float tv = tel[r][k];
                acc[r].x = fmaf(tv, wv.x, acc[r].x);
                acc[r].y = fmaf(tv, wv.y, acc[r].y);
                acc[r].z = fmaf(tv, wv.z, acc[r].z);
                acc[r].w = fmaf(tv, wv.w, acc[r].w);
            }
        }
        #pragma unroll
        for (int off = 16; off <= 32; off <<= 1) {
            #pragma unroll
            for (int r = 0; r < 4; ++r) {
                acc[r].x += __shfl_down(acc[r].x, off);
                acc[r].y += __shfl_down(acc[r].y, off);
                acc[r].z += __shfl_down(acc[r].z, off);
                acc[r].w += __shfl_down(acc[r].w, off);
            }
        }
        if (lane < 16) {
            #pragma unroll
            for (int r = 0; r < 4; ++r)
                *(float4*)&part[m][h][r][cg] = acc[r];
        }
        __syncthreads();

        {
            // 256 threads write 2 mats x 4 rows x 64 cols = 512 values
            const int mm = t >> 7, col = t & 63, rr = (t >> 6) & 1;
            const float bb = mm ? bvs[col] : bks[col];
            float* dst = mm ? vsw : ksw;
            #pragma unroll
            for (int r = rr; r < 4; r += 2) {
                const float v = part[mm][0][r][col] + part[mm][1][r][col] + bb;
                dst[(size_t)(row0 + r) * NC + col] = v;
            }
        }
    }
}

// ---------------------------------------------------------------------------
// Kernel 2: per-batch reductions. M = vs^T ks, Ks = sum_s ks, Vs = sum_s vs.
// 256 blocks (b,c) x 256 thr; wave w covers s in [64w, 64w+64).
// ---------------------------------------------------------------------------
__global__ __launch_bounds__(256) void reduce_kernel(
    const float* __restrict__ ksw, const float* __restrict__ vsw,
    float* __restrict__ Mw, float* __restrict__ Ksw, float* __restrict__ Vsw)
{
    __shared__ float pm[4][NC], pk[4][NC], pv[4];
    const int t = threadIdx.x, w = t >> 6, d = t & 63;
    const int b = blockIdx.x >> 6, c = blockIdx.x & 63;
    const float* __restrict__ vsb = vsw + (size_t)b * SS * NC;
    const float* __restrict__ ksb = ksw + (size_t)b * SS * NC;
    float acc = 0.f, ks_ = 0.f, vs_ = 0.f;
    #pragma unroll 4
    for (int j = 0; j < 64; ++j) {
        const int s2 = w * 64 + j;
        const float vv = vsb[s2 * NC + c];
        const float kv = ksb[s2 * NC + d];
        acc = fmaf(vv, kv, acc);
        ks_ += kv; vs_ += vv;
    }
    pm[w][d] = acc; pk[w][d] = ks_;
    if (d == 0) pv[w] = vs_;
    __syncthreads();
    if (t < 64) {
        Mw[((size_t)b * NC + c) * NC + t] = pm[0][t] + pm[1][t] + pm[2][t] + pm[3][t];
        if (c == 0) Ksw[b * NC + t] = pk[0][t] + pk[1][t] + pk[2][t] + pk[3][t];
        if (t == 0) Vsw[b * NC + c] = pv[0] + pv[1] + pv[2] + pv[3];
    }
}

// ---------------------------------------------------------------------------
// Kernel 3: per-pixel attention + out proj + residual + LN. Projections come
// precomputed in P. 1024 blocks x 256 thr, 4 pixels/block.
// A[c,d] = ((256*vx[c]+Vs[c])*kx[d] + vx[c]*Ks[d] + M[c,d]) / 8
// ---------------------------------------------------------------------------
__global__ __launch_bounds__(256) void pixel_kernel(
    const float* __restrict__ x, const float* __restrict__ P,
    const float* __restrict__ Wout, const float* __restrict__ bout,
    const float* __restrict__ ln_scale, const float* __restrict__ ln_bias,
    const float* __restrict__ Mw, const float* __restrict__ Ksw,
    const float* __restrict__ Vsw,
    float* __restrict__ out)
{
    __shared__ float Ml[NC * 65];
    __shared__ float projl[PXB][192];
    __shared__ float xl[PXB][CC];
    __shared__ float rsl[PXB][NC];
    __shared__ float mxl[PXB][NC];
    __shared__ float outl[PXB][NC];
    __shared__ float Ksl[NC], Vsl[NC];
    __shared__ float redl[2][2][4];

    const int t = threadIdx.x;
    const int w = t >> 6, lane = t & 63;
    const int px0g = blockIdx.x * PXB;
    const int b = px0g >> 10;

    {
        const float4* P4 = (const float4*)(P + (size_t)px0g * 192);
        for (int i = t; i < PXB * 192 / 4; i += 256)
            ((float4*)&projl[0][0])[i] = P4[i];
        const float4* x4 = (const float4*)(x + (size_t)px0g * CC);
        for (int i = t; i < PXB * CC / 4; i += 256)
            ((float4*)&xl[0][0])[i] = x4[i];
        const float* Mb = Mw + (size_t)b * NC * NC;
        for (int i = t; i < NC * NC; i += 256)
            Ml[(i >> 6) * 65 + (i & 63)] = Mb[i];
        if (t < NC) { Ksl[t] = Ksw[b * NC + t]; Vsl[t] = Vsw[b * NC + t]; }
    }
    __syncthreads();

    // ---- pass 1: wave = pixel, lane = row c: softmax stats (A recomputed) ----
    {
        const int px = w, c = lane;
        const float vxc = projl[px][128 + c];
        const float qc  = projl[px][c];
        const float uc  = fmaf(256.0f, vxc, Vsl[c]);
        float mx = -3.4e38f;
        #pragma unroll
        for (int d = 0; d < NC; ++d) {
            const float A = fmaf(uc, projl[px][64 + d],
                                 fmaf(vxc, Ksl[d], Ml[c * 65 + d])) * 0.125f;
            mx = fmaxf(mx, A);
        }
        float sum = 0.f;
        #pragma unroll
        for (int d = 0; d < NC; ++d) {
            const float A = fmaf(uc, projl[px][64 + d],
                                 fmaf(vxc, Ksl[d], Ml[c * 65 + d])) * 0.125f;
            sum += __expf(A - mx);
        }
        rsl[px][c] = qc / sum;
        mxl[px][c] = mx;
    }
    __syncthreads();

    // ---- pass 2: wave = pixel, lane = col d ----
    {
        const int px = w, d = lane;
        const float kxd = projl[px][64 + d];
        const float Ksd = Ksl[d];
        float acc = 0.f;
        #pragma unroll 4
        for (int c = 0; c < NC; ++c) {
            const float vxc = projl[px][128 + c];
            const float uc = fmaf(256.0f, vxc, Vsl[c]);
            const float A = fmaf(uc, kxd, fmaf(vxc, Ksd, Ml[c * 65 + d])) * 0.125f;
            acc = fmaf(rsl[px][c], __expf(A - mxl[px][c]), acc);
        }
        outl[px][d] = acc;
    }
    __syncthreads();

    // ---- out proj + residual + layernorm ----
    {
        const int col = t & 127;
        const int pxg = t >> 7;
        const int px0 = 2 * pxg, px1 = px0 + 1;
        float acc0 = 0.f, acc1 = 0.f;
        #pragma unroll 4
        for (int k = 0; k < NC; ++k) {
            const float wv = Wout[k * CC + col];
            acc0 = fmaf(outl[px0][k], wv, acc0);
            acc1 = fmaf(outl[px1][k], wv, acc1);
        }
        const float bb = bout[col];
        const float y0 = acc0 + bb + xl[px0][col];
        const float y1 = acc1 + bb + xl[px1][col];

        float s10 = y0, s20 = y0 * y0, s11 = y1, s21 = y1 * y1;
        #pragma unroll
        for (int off = 32; off >= 1; off >>= 1) {
            s10 += __shfl_down(s10, off);
            s20 += __shfl_down(s20, off);
            s11 += __shfl_down(s11, off);
            s21 += __shfl_down(s21, off);
        }
        const int half = (t >> 6) & 1;
        if (lane == 0) {
            redl[pxg][half][0] = s10; redl[pxg][half][1] = s20;
            redl[pxg][half][2] = s11; redl[pxg][half][3] = s21;
        }
        __syncthreads();
        const float S10 = redl[pxg][0][0] + redl[pxg][1][0];
        const float S20 = redl[pxg][0][1] + redl[pxg][1][1];
        const float S11 = redl[pxg][0][2] + redl[pxg][1][2];
        const float S21 = redl[pxg][0][3] + redl[pxg][1][3];
        const float mu0 = S10 * (1.f / 128.f);
        const float var0 = S20 * (1.f / 128.f) - mu0 * mu0;
        const float mu1 = S11 * (1.f / 128.f);
        const float var1 = S21 * (1.f / 128.f) - mu1 * mu1;
        const float r0 = rsqrtf(var0 + 1e-6f), r1 = rsqrtf(var1 + 1e-6f);
        const float gg = ln_scale[col], be = ln_bias[col];
        out[(size_t)(px0g + px0) * CC + col] = (y0 - mu0) * r0 * gg + be;
        out[(size_t)(px0g + px1) * CC + col] = (y1 - mu1) * r1 * gg + be;
    }
}

// ---------------------------------------------------------------------------
extern "C" void kernel_launch(void* const* d_in, const int* in_sizes, int n_in,
                              void* d_out, int out_size, void* d_ws, size_t ws_size,
                              hipStream_t stream) {
    const float* x        = (const float*)d_in[0];
    const float* s        = (const float*)d_in[1];
    const float* a        = (const float*)d_in[2];
    const float* Wq       = (const float*)d_in[3];
    const float* bq       = (const float*)d_in[4];
    const float* Wkx      = (const float*)d_in[5];
    const float* bkx      = (const float*)d_in[6];
    const float* Wvx      = (const float*)d_in[7];
    const float* bvx      = (const float*)d_in[8];
    const float* Wks      = (const float*)d_in[9];
    const float* bks      = (const float*)d_in[10];
    const float* Wvs      = (const float*)d_in[11];
    const float* bvs      = (const float*)d_in[12];
    const float* Wout     = (const float*)d_in[13];
    const float* bout     = (const float*)d_in[14];
    const float* ln_scale = (const float*)d_in[15];
    const float* ln_bias  = (const float*)d_in[16];

    float* ws  = (float*)d_ws;
    float* ksw = ws;                 // 65536
    float* vsw = ws + 65536;         // 65536
    float* Mw  = ws + 131072;        // 16384
    float* Ksw = ws + 147456;        // 256
    float* Vsw = ws + 147712;        // 256
    float* Pw  = ws + 147968;        // 4096*192 = 786432

    fused_proj_kernel<<<768, 256, 0, stream>>>(
        x, Wq, bq, Wkx, bkx, Wvx, bvx, s, a, Wks, bks, Wvs, bvs, Pw, ksw, vsw);
    reduce_kernel<<<BB * NC, 256, 0, stream>>>(ksw, vsw, Mw, Ksw, Vsw);
    pixel_kernel<<<(BB * 1024) / PXB, 256, 0, stream>>>(
        x, Pw, Wout, bout, ln_scale, ln_bias, Mw, Ksw, Vsw, (float*)d_out);
}

// Round 4
// 117.277 us; speedup vs baseline: 1.0528x; 1.0148x over previous
//
#include <hip/hip_runtime.h>
#include <hip/hip_bf16.h>

#define BB 4
#define SS 256
#define DD 512
#define CC 128
#define NC 64
#define PXB 4    // pixels per block in pixel kernel

// ---------------------------------------------------------------------------
// Kernel 1 (fused): blocks 0..511 = x projections (8 px/block),
//                   blocks 512..1023 = text projections (2 rows/block).
// Both roles: 256 threads, float4 weight loads, shuffle-reduce over k-sublanes.
// xproj output P[px][0:64]=q, [64:128]=kx, [128:192]=vx.
// (Byte-identical to the proven 117.1 us version.)
// ---------------------------------------------------------------------------
__global__ __launch_bounds__(256) void fused_proj_kernel(
    const float* __restrict__ x,
    const float* __restrict__ Wq,  const float* __restrict__ bq,
    const float* __restrict__ Wkx, const float* __restrict__ bkx,
    const float* __restrict__ Wvx, const float* __restrict__ bvx,
    const float* __restrict__ s, const float* __restrict__ a,
    const float* __restrict__ Wks, const float* __restrict__ bks,
    const float* __restrict__ Wvs, const float* __restrict__ bvs,
    float* __restrict__ P, float* __restrict__ ksw, float* __restrict__ vsw)
{
    __shared__ float tel[2][DD];          // text role
    __shared__ float part[2][2][2][NC];   // text role
    __shared__ float xl[8][CC];           // xproj role

    const int t = threadIdx.x;
    const int w = t >> 6, lane = t & 63;

    if (blockIdx.x < 512) {
        // ---------------- xproj role ----------------
        const int px0 = blockIdx.x * 8;
        {
            const float4* x4 = (const float4*)(x + (size_t)px0 * CC);
            ((float4*)&xl[0][0])[t] = x4[t];    // 256 float4 = 8*128 floats
        }
        __syncthreads();
        if (w < 3) {
            const float* __restrict__ Wm = (w == 0) ? Wq : (w == 1 ? Wkx : Wvx);
            const float* __restrict__ bm = (w == 0) ? bq : (w == 1 ? bkx : bvx);
            const int ksub = lane >> 4;        // 0..3
            const int cg = (lane & 15) * 4;    // col group base
            float4 acc[8] = {};
            #pragma unroll 4
            for (int j = 0; j < 32; ++j) {
                const int k = 4 * j + ksub;
                const float4 wv = *(const float4*)(Wm + (size_t)k * NC + cg);
                #pragma unroll
                for (int px = 0; px < 8; ++px) {
                    const float xv = xl[px][k];
                    acc[px].x = fmaf(xv, wv.x, acc[px].x);
                    acc[px].y = fmaf(xv, wv.y, acc[px].y);
                    acc[px].z = fmaf(xv, wv.z, acc[px].z);
                    acc[px].w = fmaf(xv, wv.w, acc[px].w);
                }
            }
            #pragma unroll
            for (int px = 0; px < 8; ++px) {
                #pragma unroll
                for (int off = 16; off <= 32; off <<= 1) {
                    acc[px].x += __shfl_down(acc[px].x, off);
                    acc[px].y += __shfl_down(acc[px].y, off);
                    acc[px].z += __shfl_down(acc[px].z, off);
                    acc[px].w += __shfl_down(acc[px].w, off);
                }
            }
            if (ksub == 0) {
                const float4 bb = *(const float4*)(bm + cg);
                #pragma unroll
                for (int px = 0; px < 8; ++px) {
                    float4 v;
                    v.x = acc[px].x + bb.x; v.y = acc[px].y + bb.y;
                    v.z = acc[px].z + bb.z; v.w = acc[px].w + bb.w;
                    *(float4*)(P + (size_t)(px0 + px) * 192 + w * 64 + cg) = v;
                }
            }
        }
    } else {
        // ---------------- text role ----------------
        const int row0 = (blockIdx.x - 512) * 2;
        {
            const float4* s4 = (const float4*)(s + (size_t)row0 * DD);
            const int r = t >> 7;
            const float am = a[row0 + r];
            float4 v = s4[t];
            v.x *= am; v.y *= am; v.z *= am; v.w *= am;
            ((float4*)&tel[0][0])[t] = v;
        }
        __syncthreads();

        const int m = w & 1, h = w >> 1;
        const int kb = h * 256;
        const int cg = (lane & 15) * 4;
        const int ksub = lane >> 4;
        const float* __restrict__ Wm = m ? Wvs : Wks;

        float4 acc0 = {0,0,0,0}, acc1 = {0,0,0,0};
        #pragma unroll 4
        for (int j = 0; j < 64; ++j) {
            const int k = kb + 4 * j + ksub;
            const float4 wv = *(const float4*)(Wm + (size_t)k * NC + cg);
            const float t0 = tel[0][k];
            const float t1 = tel[1][k];
            acc0.x = fmaf(t0, wv.x, acc0.x); acc0.y = fmaf(t0, wv.y, acc0.y);
            acc0.z = fmaf(t0, wv.z, acc0.z); acc0.w = fmaf(t0, wv.w, acc0.w);
            acc1.x = fmaf(t1, wv.x, acc1.x); acc1.y = fmaf(t1, wv.y, acc1.y);
            acc1.z = fmaf(t1, wv.z, acc1.z); acc1.w = fmaf(t1, wv.w, acc1.w);
        }
        #pragma unroll
        for (int off = 16; off <= 32; off <<= 1) {
            acc0.x += __shfl_down(acc0.x, off); acc0.y += __shfl_down(acc0.y, off);
            acc0.z += __shfl_down(acc0.z, off); acc0.w += __shfl_down(acc0.w, off);
            acc1.x += __shfl_down(acc1.x, off); acc1.y += __shfl_down(acc1.y, off);
            acc1.z += __shfl_down(acc1.z, off); acc1.w += __shfl_down(acc1.w, off);
        }
        if (lane < 16) {
            *(float4*)&part[m][h][0][cg] = acc0;
            *(float4*)&part[m][h][1][cg] = acc1;
        }
        __syncthreads();

        {
            const int mm = t >> 7, r = (t >> 6) & 1, col = t & 63;
            const float v = part[mm][0][r][col] + part[mm][1][r][col]
                          + (mm ? bvs[col] : bks[col]);
            float* dst = mm ? vsw : ksw;
            dst[(size_t)(row0 + r) * NC + col] = v;
        }
    }
}

// ---------------------------------------------------------------------------
// Kernel 2: per-batch reductions. M = vs^T ks, Ks = sum_s ks, Vs = sum_s vs.
// 256 blocks (b,c) x 1024 thr (16 waves); wave w covers s in [16w, 16w+16).
// Same memory pattern as the 256-thr version (d-lanes coalesced, c broadcast)
// but 4x the waves/SIMD for latency hiding (was the 1-wave/SIMD weak link).
// ---------------------------------------------------------------------------
__global__ __launch_bounds__(1024) void reduce_kernel(
    const float* __restrict__ ksw, const float* __restrict__ vsw,
    float* __restrict__ Mw, float* __restrict__ Ksw, float* __restrict__ Vsw)
{
    __shared__ float pm[16][NC], pk[16][NC], pv[16];
    const int t = threadIdx.x, w = t >> 6, d = t & 63;
    const int b = blockIdx.x >> 6, c = blockIdx.x & 63;
    const float* __restrict__ vsb = vsw + (size_t)b * SS * NC;
    const float* __restrict__ ksb = ksw + (size_t)b * SS * NC;
    float acc = 0.f, ks_ = 0.f, vs_ = 0.f;
    #pragma unroll
    for (int j = 0; j < 16; ++j) {
        const int s2 = w * 16 + j;
        const float vv = vsb[s2 * NC + c];
        const float kv = ksb[s2 * NC + d];
        acc = fmaf(vv, kv, acc);
        ks_ += kv; vs_ += vv;
    }
    pm[w][d] = acc; pk[w][d] = ks_;
    if (d == 0) pv[w] = vs_;
    __syncthreads();
    if (t < 64) {
        float sm = 0.f, sk = 0.f, sv = 0.f;
        #pragma unroll
        for (int i = 0; i < 16; ++i) {
            sm += pm[i][t]; sk += pk[i][t]; sv += pv[i];
        }
        Mw[((size_t)b * NC + c) * NC + t] = sm;
        if (c == 0) Ksw[b * NC + t] = sk;
        if (t == 0) Vsw[b * NC + c] = sv;
    }
}

// ---------------------------------------------------------------------------
// Kernel 3: per-pixel attention + out proj + residual + LN. Projections come
// precomputed in P. 1024 blocks x 256 thr, 4 pixels/block.
// A[c,d] = ((256*vx[c]+Vs[c])*kx[d] + vx[c]*Ks[d] + M[c,d]) / 8
// (Byte-identical to the proven 117.1 us version.)
// ---------------------------------------------------------------------------
__global__ __launch_bounds__(256) void pixel_kernel(
    const float* __restrict__ x, const float* __restrict__ P,
    const float* __restrict__ Wout, const float* __restrict__ bout,
    const float* __restrict__ ln_scale, const float* __restrict__ ln_bias,
    const float* __restrict__ Mw, const float* __restrict__ Ksw,
    const float* __restrict__ Vsw,
    float* __restrict__ out)
{
    __shared__ float Ml[NC * 65];
    __shared__ float projl[PXB][192];
    __shared__ float xl[PXB][CC];
    __shared__ float rsl[PXB][NC];
    __shared__ float mxl[PXB][NC];
    __shared__ float outl[PXB][NC];
    __shared__ float Ksl[NC], Vsl[NC];
    __shared__ float redl[2][2][4];

    const int t = threadIdx.x;
    const int w = t >> 6, lane = t & 63;
    const int px0g = blockIdx.x * PXB;
    const int b = px0g >> 10;

    {
        const float4* P4 = (const float4*)(P + (size_t)px0g * 192);
        for (int i = t; i < PXB * 192 / 4; i += 256)
            ((float4*)&projl[0][0])[i] = P4[i];
        const float4* x4 = (const float4*)(x + (size_t)px0g * CC);
        for (int i = t; i < PXB * CC / 4; i += 256)
            ((float4*)&xl[0][0])[i] = x4[i];
        const float* Mb = Mw + (size_t)b * NC * NC;
        for (int i = t; i < NC * NC; i += 256)
            Ml[(i >> 6) * 65 + (i & 63)] = Mb[i];
        if (t < NC) { Ksl[t] = Ksw[b * NC + t]; Vsl[t] = Vsw[b * NC + t]; }
    }
    __syncthreads();

    // ---- pass 1: wave = pixel, lane = row c: softmax stats (A recomputed) ----
    {
        const int px = w, c = lane;
        const float vxc = projl[px][128 + c];
        const float qc  = projl[px][c];
        const float uc  = fmaf(256.0f, vxc, Vsl[c]);
        float mx = -3.4e38f;
        #pragma unroll
        for (int d = 0; d < NC; ++d) {
            const float A = fmaf(uc, projl[px][64 + d],
                                 fmaf(vxc, Ksl[d], Ml[c * 65 + d])) * 0.125f;
            mx = fmaxf(mx, A);
        }
        float sum = 0.f;
        #pragma unroll
        for (int d = 0; d < NC; ++d) {
            const float A = fmaf(uc, projl[px][64 + d],
                                 fmaf(vxc, Ksl[d], Ml[c * 65 + d])) * 0.125f;
            sum += __expf(A - mx);
        }
        rsl[px][c] = qc / sum;
        mxl[px][c] = mx;
    }
    __syncthreads();

    // ---- pass 2: wave = pixel, lane = col d ----
    {
        const int px = w, d = lane;
        const float kxd = projl[px][64 + d];
        const float Ksd = Ksl[d];
        float acc = 0.f;
        #pragma unroll 4
        for (int c = 0; c < NC; ++c) {
            const float vxc = projl[px][128 + c];
            const float uc = fmaf(256.0f, vxc, Vsl[c]);
            const float A = fmaf(uc, kxd, fmaf(vxc, Ksd, Ml[c * 65 + d])) * 0.125f;
            acc = fmaf(rsl[px][c], __expf(A - mxl[px][c]), acc);
        }
        outl[px][d] = acc;
    }
    __syncthreads();

    // ---- out proj + residual + layernorm ----
    {
        const int col = t & 127;
        const int pxg = t >> 7;
        const int px0 = 2 * pxg, px1 = px0 + 1;
        float acc0 = 0.f, acc1 = 0.f;
        #pragma unroll 4
        for (int k = 0; k < NC; ++k) {
            const float wv = Wout[k * CC + col];
            acc0 = fmaf(outl[px0][k], wv, acc0);
            acc1 = fmaf(outl[px1][k], wv, acc1);
        }
        const float bb = bout[col];
        const float y0 = acc0 + bb + xl[px0][col];
        const float y1 = acc1 + bb + xl[px1][col];

        float s10 = y0, s20 = y0 * y0, s11 = y1, s21 = y1 * y1;
        #pragma unroll
        for (int off = 32; off >= 1; off >>= 1) {
            s10 += __shfl_down(s10, off);
            s20 += __shfl_down(s20, off);
            s11 += __shfl_down(s11, off);
            s21 += __shfl_down(s21, off);
        }
        const int half = (t >> 6) & 1;
        if (lane == 0) {
            redl[pxg][half][0] = s10; redl[pxg][half][1] = s20;
            redl[pxg][half][2] = s11; redl[pxg][half][3] = s21;
        }
        __syncthreads();
        const float S10 = redl[pxg][0][0] + redl[pxg][1][0];
        const float S20 = redl[pxg][0][1] + redl[pxg][1][1];
        const float S11 = redl[pxg][0][2] + redl[pxg][1][2];
        const float S21 = redl[pxg][0][3] + redl[pxg][1][3];
        const float mu0 = S10 * (1.f / 128.f);
        const float var0 = S20 * (1.f / 128.f) - mu0 * mu0;
        const float mu1 = S11 * (1.f / 128.f);
        const float var1 = S21 * (1.f / 128.f) - mu1 * mu1;
        const float r0 = rsqrtf(var0 + 1e-6f), r1 = rsqrtf(var1 + 1e-6f);
        const float gg = ln_scale[col], be = ln_bias[col];
        out[(size_t)(px0g + px0) * CC + col] = (y0 - mu0) * r0 * gg + be;
        out[(size_t)(px0g + px1) * CC + col] = (y1 - mu1) * r1 * gg + be;
    }
}

// ---------------------------------------------------------------------------
extern "C" void kernel_launch(void* const* d_in, const int* in_sizes, int n_in,
                              void* d_out, int out_size, void* d_ws, size_t ws_size,
                              hipStream_t stream) {
    const float* x        = (const float*)d_in[0];
    const float* s        = (const float*)d_in[1];
    const float* a        = (const float*)d_in[2];
    const float* Wq       = (const float*)d_in[3];
    const float* bq       = (const float*)d_in[4];
    const float* Wkx      = (const float*)d_in[5];
    const float* bkx      = (const float*)d_in[6];
    const float* Wvx      = (const float*)d_in[7];
    const float* bvx      = (const float*)d_in[8];
    const float* Wks      = (const float*)d_in[9];
    const float* bks      = (const float*)d_in[10];
    const float* Wvs      = (const float*)d_in[11];
    const float* bvs      = (const float*)d_in[12];
    const float* Wout     = (const float*)d_in[13];
    const float* bout     = (const float*)d_in[14];
    const float* ln_scale = (const float*)d_in[15];
    const float* ln_bias  = (const float*)d_in[16];

    float* ws  = (float*)d_ws;
    float* ksw = ws;                 // 65536
    float* vsw = ws + 65536;         // 65536
    float* Mw  = ws + 131072;        // 16384
    float* Ksw = ws + 147456;        // 256
    float* Vsw = ws + 147712;        // 256
    float* Pw  = ws + 147968;        // 4096*192 = 786432

    fused_proj_kernel<<<1024, 256, 0, stream>>>(
        x, Wq, bq, Wkx, bkx, Wvx, bvx, s, a, Wks, bks, Wvs, bvs, Pw, ksw, vsw);
    reduce_kernel<<<BB * NC, 1024, 0, stream>>>(ksw, vsw, Mw, Ksw, Vsw);
    pixel_kernel<<<(BB * 1024) / PXB, 256, 0, stream>>>(
        x, Pw, Wout, bout, ln_scale, ln_bias, Mw, Ksw, Vsw, (float*)d_out);
}